// Round 1
// baseline (738.516 us; speedup 1.0000x reference)
//
#include <hip/hip_runtime.h>
#include <hip/hip_bf16.h>
#include <stdint.h>

#define BB   4
#define NN   100000
#define DIN  16
#define DF   19          // 16 features + 3 voxel deltas
#define KO   128         // MLP width
#define GX   468
#define GY   468
#define VOL  (GX * GY)   // z-dim is 1

// ---------------------------------------------------------------------------
// point_mask dtype detection: the harness may hand us bool as uint8 (1B),
// int32 (4B, values 0/1) or float32 (4B, 0.0/1.0). Scan the first 64KB of
// bytes (safe: smallest possible buffer is 400000 B):
//   uint8  (95% ones): nonzero bytes at pos%4!=0 AND pos%4==0
//   int32  (0/1):      nonzero bytes only at pos%4==0
//   float32 (1.0f):    nonzero bytes only at pos%4!=0 (bytes 0x80,0x3f)
// -> elem4 ("treat as 4-byte word, nonzero == true") iff NOT(uint8 pattern).
// ---------------------------------------------------------------------------
__global__ void detect_mask_kind(const unsigned char* __restrict__ mask_bytes,
                                 int* __restrict__ flag) {
    __shared__ int sA, sB;
    if (threadIdx.x == 0) { sA = 0; sB = 0; }
    __syncthreads();
    int a = 0, b = 0;
    for (int i = threadIdx.x; i < 65536; i += blockDim.x) {
        unsigned char v = mask_bytes[i];
        if (v) { if (i & 3) a = 1; else b = 1; }
    }
    if (a) atomicOr(&sA, 1);
    if (b) atomicOr(&sB, 1);
    __syncthreads();
    if (threadIdx.x == 0) {
        int is_u8 = (sA && sB);
        flag[0] = is_u8 ? 1 : 4;
    }
}

// ---------------------------------------------------------------------------
// Per point: voxel id + dense(19->128) + ReLU + atomicMax scatter.
// 256 threads/block = 2 points per iteration, 128 threads (= output lanes)
// per point. W (19x128 = 9.7KB) staged in LDS once per block.
// ---------------------------------------------------------------------------
__global__ __launch_bounds__(256) void voxelize_kernel(
    const float* __restrict__ xyz,       // [B*N, 3]
    const float* __restrict__ pfeat,     // [B*N, 16]
    const unsigned char* __restrict__ mask_raw,
    const float* __restrict__ W,         // [19, 128] row-major
    const float* __restrict__ bias,      // [128]
    const int*   __restrict__ flag,      // [1] from detect_mask_kind
    float* __restrict__ out)             // [B*VOL, 128], pre-zeroed
{
    __shared__ float sW[DF * KO];
    __shared__ float sb[KO];
    __shared__ float sfeat[2][DF];
    __shared__ int   svid[2];

    for (int i = threadIdx.x; i < DF * KO; i += 256) sW[i] = W[i];
    if (threadIdx.x < KO) sb[threadIdx.x] = bias[threadIdx.x];

    const int elem4 = (flag[0] == 4);
    const int total = BB * NN;
    const int half  = threadIdx.x >> 7;   // which of the 2 points
    const int k     = threadIdx.x & 127;  // output lane

    for (int base = blockIdx.x * 2; base < total; base += gridDim.x * 2) {
        const int p = base + half;
        __syncthreads();   // protects sW on iter 0, sfeat/svid reuse after

        if (p < total) {
            if (k < DIN) sfeat[half][k] = pfeat[p * DIN + k];
            if (k == 0) {
                const float x = xyz[p * 3 + 0];
                const float y = xyz[p * 3 + 1];
                const float z = xyz[p * 3 + 2];
                const float fx = floorf(x / 0.32f);
                const float fy = floorf(y / 0.32f);
                const float fz = floorf(z / 6.0f);
                sfeat[half][16] = x - fx * 0.32f;
                sfeat[half][17] = y - fy * 0.32f;
                sfeat[half][18] = z - fz * 6.0f;
                const int ix = (int)fx + 234;
                const int iy = (int)fy + 234;
                const int iz = (int)fz + 1;
                const bool inb = ((unsigned)ix < (unsigned)GX) &
                                 ((unsigned)iy < (unsigned)GY) &
                                 (iz == 0);
                bool m;
                if (elem4) m = (((const int*)mask_raw)[p] != 0);
                else       m = (mask_raw[p] != 0);
                const int bidx = p / NN;
                svid[half] = (inb && m) ? (bidx * VOL + ix * GY + iy) : -1;
            }
        }
        __syncthreads();

        if (p < total) {
            const int vid = svid[half];
            if (vid >= 0) {
                float acc = sb[k];
                #pragma unroll
                for (int d = 0; d < DF; ++d)
                    acc = fmaf(sfeat[half][d], sW[d * KO + k], acc);
                acc = fmaxf(acc, 0.0f);
                if (acc > 0.0f) {
                    // nonneg float bit pattern is monotone as int
                    atomicMax((int*)(out + (size_t)vid * KO + k),
                              __float_as_int(acc));
                }
            }
        }
    }
}

extern "C" void kernel_launch(void* const* d_in, const int* in_sizes, int n_in,
                              void* d_out, int out_size, void* d_ws, size_t ws_size,
                              hipStream_t stream) {
    const float* xyz   = (const float*)d_in[0];
    const float* pfeat = (const float*)d_in[1];
    const unsigned char* mask = (const unsigned char*)d_in[2];
    const float* W     = (const float*)d_in[3];
    const float* bias  = (const float*)d_in[4];
    float* out = (float*)d_out;
    int*   flag = (int*)d_ws;

    // output is poisoned 0xAA before every timed launch -> zero it.
    hipMemsetAsync(d_out, 0, (size_t)out_size * sizeof(float), stream);
    detect_mask_kind<<<1, 256, 0, stream>>>(mask, flag);
    voxelize_kernel<<<4096, 256, 0, stream>>>(xyz, pfeat, mask, W, bias, flag, out);
}

// Round 2
// 595.565 us; speedup vs baseline: 1.2400x; 1.2400x over previous
//
#include <hip/hip_runtime.h>
#include <hip/hip_bf16.h>
#include <stdint.h>

#define BB   4
#define NN   100000
#define DIN  16
#define DF   19          // 16 features + 3 voxel deltas
#define KO   128         // MLP width
#define GX   468
#define GY   468
#define VOL  (GX * GY)   // z-dim is 1
#define TOTAL (BB * NN)

// ---------------------------------------------------------------------------
// Zero-fill d_out with float4 stores (hipMemsetAsync's rocclr fill measured
// only ~1.5 TB/s effective; a plain grid-stride dwordx4 store kernel should
// run at write-BW ceiling).
// ---------------------------------------------------------------------------
__global__ __launch_bounds__(256) void zero_fill(float4* __restrict__ out, int n4) {
    int i = blockIdx.x * 256 + threadIdx.x;
    const int stride = gridDim.x * 256;
    const float4 z = make_float4(0.f, 0.f, 0.f, 0.f);
    for (; i < n4; i += stride) out[i] = z;
}

// ---------------------------------------------------------------------------
// point_mask dtype detection (bool may arrive as uint8 / int32 / float32).
// Scan first 16 KB as uint4:
//   uint8 (95% ones): nonzero low byte AND nonzero high bytes in words
//   int32 (0/1):      nonzero low byte only
//   float32 (1.0f=0x3f800000): nonzero high bytes only
// elem4 ("read as 4-byte word") unless uint8 pattern.
// ---------------------------------------------------------------------------
__global__ void detect_mask_kind(const uint4* __restrict__ mask_words,
                                 int* __restrict__ flag) {
    __shared__ int sA, sB;
    if (threadIdx.x == 0) { sA = 0; sB = 0; }
    __syncthreads();
    int a = 0, b = 0;
    #pragma unroll
    for (int it = 0; it < 4; ++it) {
        uint4 w = mask_words[it * 256 + threadIdx.x];
        unsigned lo = (w.x & 0xFFu) | (w.y & 0xFFu) | (w.z & 0xFFu) | (w.w & 0xFFu);
        unsigned hi = (w.x & 0xFFFFFF00u) | (w.y & 0xFFFFFF00u) |
                      (w.z & 0xFFFFFF00u) | (w.w & 0xFFFFFF00u);
        if (hi) a = 1;
        if (lo) b = 1;
    }
    if (a) atomicOr(&sA, 1);
    if (b) atomicOr(&sB, 1);
    __syncthreads();
    if (threadIdx.x == 0) flag[0] = (sA && sB) ? 1 : 4;
}

// ---------------------------------------------------------------------------
// Wave-per-point: each 64-lane wave owns a contiguous chunk of points.
// All lanes broadcast-load the point (wave-uniform address -> 1 transaction),
// lane handles output channels k=lane and k+64. W in LDS (read addr
// d*128+lane: 2-way bank aliasing, free on gfx950). No barriers in the loop.
// Scatter via bitwise-int atomicMax (exact for nonneg floats on a zeroed
// buffer); zero results skipped.
// ---------------------------------------------------------------------------
__global__ __launch_bounds__(256) void voxelize_kernel(
    const float* __restrict__ xyz,       // [B*N, 3]
    const float* __restrict__ pfeat,     // [B*N, 16]
    const unsigned char* __restrict__ mask_raw,
    const float* __restrict__ W,         // [19, 128] row-major
    const float* __restrict__ bias,      // [128]
    const int*   __restrict__ flag,      // [1]
    float* __restrict__ out)             // [B*VOL, 128], pre-zeroed
{
    __shared__ float sW[DF * KO];
    __shared__ float sb[KO];
    for (int i = threadIdx.x; i < DF * KO; i += 256) sW[i] = W[i];
    if (threadIdx.x < KO) sb[threadIdx.x] = bias[threadIdx.x];
    __syncthreads();

    const int elem4 = (flag[0] == 4);
    const int lane  = threadIdx.x & 63;
    const int wave  = blockIdx.x * 4 + (threadIdx.x >> 6);
    const int nwaves = gridDim.x * 4;
    const int chunk = (TOTAL + nwaves - 1) / nwaves;
    const int p0 = wave * chunk;
    const int p1 = min(p0 + chunk, TOTAL);

    const float b0 = sb[lane];
    const float b1 = sb[lane + 64];

    for (int p = p0; p < p1; ++p) {
        // wave-uniform scalar work (every lane computes the same thing)
        const float x = xyz[p * 3 + 0];
        const float y = xyz[p * 3 + 1];
        const float z = xyz[p * 3 + 2];
        bool m;
        if (elem4) m = (((const int*)mask_raw)[p] != 0);
        else       m = (mask_raw[p] != 0);
        const float fx = floorf(x / 0.32f);
        const float fy = floorf(y / 0.32f);
        const float fz = floorf(z / 6.0f);
        const int ix = (int)fx + 234;
        const int iy = (int)fy + 234;
        const int iz = (int)fz + 1;
        const bool inb = ((unsigned)ix < (unsigned)GX) &
                         ((unsigned)iy < (unsigned)GY) &
                         (iz == 0) & m;
        if (!inb) continue;   // wave-uniform branch

        float f[DF];
        const float4* pf4 = (const float4*)(pfeat + (size_t)p * DIN);
        float4 v0 = pf4[0], v1 = pf4[1], v2 = pf4[2], v3 = pf4[3];
        f[0]=v0.x; f[1]=v0.y; f[2]=v0.z; f[3]=v0.w;
        f[4]=v1.x; f[5]=v1.y; f[6]=v1.z; f[7]=v1.w;
        f[8]=v2.x; f[9]=v2.y; f[10]=v2.z; f[11]=v2.w;
        f[12]=v3.x; f[13]=v3.y; f[14]=v3.z; f[15]=v3.w;
        f[16] = x - fx * 0.32f;
        f[17] = y - fy * 0.32f;
        f[18] = z - fz * 6.0f;

        float acc0 = b0, acc1 = b1;
        #pragma unroll
        for (int d = 0; d < DF; ++d) {
            acc0 = fmaf(f[d], sW[d * KO + lane], acc0);
            acc1 = fmaf(f[d], sW[d * KO + 64 + lane], acc1);
        }
        acc0 = fmaxf(acc0, 0.0f);
        acc1 = fmaxf(acc1, 0.0f);

        const int bidx = p / NN;
        float* dst = out + (size_t)(bidx * VOL + ix * GY + iy) * KO;
        if (acc0 > 0.0f)
            atomicMax((int*)(dst + lane), __float_as_int(acc0));
        if (acc1 > 0.0f)
            atomicMax((int*)(dst + lane + 64), __float_as_int(acc1));
    }
}

extern "C" void kernel_launch(void* const* d_in, const int* in_sizes, int n_in,
                              void* d_out, int out_size, void* d_ws, size_t ws_size,
                              hipStream_t stream) {
    const float* xyz   = (const float*)d_in[0];
    const float* pfeat = (const float*)d_in[1];
    const unsigned char* mask = (const unsigned char*)d_in[2];
    const float* W     = (const float*)d_in[3];
    const float* bias  = (const float*)d_in[4];
    float* out = (float*)d_out;
    int*   flag = (int*)d_ws;

    const int n4 = out_size / 4;   // out_size divisible by 4 (128 channels)
    zero_fill<<<4096, 256, 0, stream>>>((float4*)out, n4);
    detect_mask_kind<<<1, 256, 0, stream>>>((const uint4*)mask, flag);
    voxelize_kernel<<<2048, 256, 0, stream>>>(xyz, pfeat, mask, W, bias, flag, out);
}